// Round 2
// baseline (353.082 us; speedup 1.0000x reference)
//
#include <hip/hip_runtime.h>

#define N_ 2048

typedef __attribute__((ext_vector_type(8))) __bf16 bf16x8;
typedef __attribute__((ext_vector_type(8))) unsigned short u16x8;
typedef __attribute__((ext_vector_type(4))) float f32x4;

__device__ inline unsigned short f2bf(float f) {
  unsigned u = __builtin_bit_cast(unsigned, f);
  u += 0x7FFFu + ((u >> 16) & 1u);   // RNE
  return (unsigned short)(u >> 16);
}
__device__ inline float bf2f(unsigned short s) {
  unsigned u = ((unsigned)s) << 16;
  return __builtin_bit_cast(float, u);
}

__device__ inline f32x4 mfma_bf16(u16x8 a, u16x8 b, f32x4 c) {
  return __builtin_amdgcn_mfma_f32_16x16x32_bf16(
      __builtin_bit_cast(bf16x8, a), __builtin_bit_cast(bf16x8, b), c, 0, 0, 0);
}

// ---------------- prep: pack weights to bf16 ----------------
__global__ __launch_bounds__(256) void prep_weights(
    const float* __restrict__ w0, const float* __restrict__ w1,
    const float* __restrict__ Wf,
    unsigned short* __restrict__ Wc1, unsigned short* __restrict__ Wc2,
    unsigned short* __restrict__ Wcat)
{
  int idx = blockIdx.x * 256 + threadIdx.x;
  if (idx < 65536) {
    int h = idx >> 14, r = (idx >> 7) & 127, k = idx & 127;
    float v = (r < 64) ? w0[(h * 64 + r) * 128 + k]
                       : w1[(h * 64 + (r - 64)) * 192 + k];
    Wc1[idx] = f2bf(v);
  } else if (idx < 81920) {
    int i = idx - 65536;
    int h = i >> 12, r = (i >> 6) & 63, k = i & 63;
    Wc2[i] = f2bf(w1[(h * 64 + r) * 192 + 128 + k]);
  } else if (idx < 163840) {
    int i = idx - 81920;
    int d = i / 640, c = i % 640;
    float v;
    if (c < 256)      { int h = c >> 6, j = c & 63;        v = Wf[d * 512 + h * 128 + j]; }
    else if (c < 512) { int h = (c - 256) >> 6, j = (c - 256) & 63; v = Wf[d * 512 + h * 128 + 64 + j]; }
    else {
      int k = c - 512; v = 0.f;
      for (int hh = 0; hh < 4; ++hh) v += Wf[d * 512 + hh * 128 + k];
    }
    Wcat[i] = f2bf(v);
  }
}

// ---------------- prep: X -> XbT (bf16 transpose [B][128][N]) + G X-slice ----------------
__global__ __launch_bounds__(256) void prep_x(
    const float* __restrict__ X, unsigned short* __restrict__ XbT,
    unsigned short* __restrict__ G)
{
  const int tid = threadIdx.x;
  const int b = blockIdx.x >> 5;
  const int n0 = (blockIdx.x & 31) * 64;
  __shared__ float tf[64][129];
  #pragma unroll
  for (int i = 0; i < 32; ++i) {
    int e = i * 256 + tid;          // 64x128 tile
    int nl = e >> 7, c = e & 127;
    float v = X[((size_t)b * N_ + n0 + nl) * 128 + c];
    tf[nl][c] = v;
    G[((size_t)b * N_ + n0 + nl) * 640 + 512 + c] = f2bf(v);
  }
  __syncthreads();
  #pragma unroll
  for (int i = 0; i < 32; ++i) {
    int e = i * 256 + tid;
    int c = e >> 6, nl = e & 63;
    XbT[((size_t)b * 128 + c) * N_ + n0 + nl] = f2bf(tf[nl][c]);
  }
}

// ---------------- pass1: Z0 = adj@X + X (bf16), denom. LDS-free, barrier-free ----------------
__global__ __launch_bounds__(256) void pass1_kernel(
    const float* __restrict__ adj, const float* __restrict__ X,
    const unsigned short* __restrict__ XbT,
    unsigned short* __restrict__ Z0b, float* __restrict__ dnm)
{
  const int tid = threadIdx.x, lane = tid & 63, w = tid >> 6;
  const int rl = lane & 15, q = lane >> 4;
  const int bh = blockIdx.y, b = bh >> 2, h = bh & 3, hb = h * 4 + b;
  const int row0 = blockIdx.x * 64 + w * 16;

  const float* aP = adj + ((size_t)bh * N_ + row0 + rl) * N_ + q * 8;
  const unsigned short* bp[8];
  #pragma unroll
  for (int ct = 0; ct < 8; ++ct)
    bp[ct] = XbT + ((size_t)b * 128 + ct * 16 + rl) * N_ + q * 8;

  f32x4 acc[8] = {};
  float rsum = 0.f;

  #pragma unroll 2
  for (int t = 0; t < 64; ++t) {
    float4 a0 = *(const float4*)(aP + (size_t)t * 32);
    float4 a1 = *(const float4*)(aP + (size_t)t * 32 + 4);
    u16x8 af;
    af[0] = f2bf(a0.x); af[1] = f2bf(a0.y); af[2] = f2bf(a0.z); af[3] = f2bf(a0.w);
    af[4] = f2bf(a1.x); af[5] = f2bf(a1.y); af[6] = f2bf(a1.z); af[7] = f2bf(a1.w);
    rsum += (a0.x + a0.y + a0.z + a0.w) + (a1.x + a1.y + a1.z + a1.w);
    #pragma unroll
    for (int ct = 0; ct < 8; ++ct) {
      u16x8 bF = *(const u16x8*)(bp[ct] + (size_t)t * 32);
      acc[ct] = mfma_bf16(af, bF, acc[ct]);
    }
  }

  rsum += __shfl_xor(rsum, 16, 64);
  rsum += __shfl_xor(rsum, 32, 64);
  if (q == 0) dnm[(size_t)hb * N_ + row0 + rl] = rsum + 1.0f;

  #pragma unroll
  for (int j = 0; j < 4; ++j) {
    const int row = q * 4 + j, n = row0 + row;
    const float* xr = X + ((size_t)b * N_ + n) * 128;
    unsigned short* zr = Z0b + ((size_t)hb * N_ + n) * 128;
    #pragma unroll
    for (int ct = 0; ct < 8; ++ct) {
      const int c = ct * 16 + rl;
      zr[c] = f2bf(acc[ct][j] + xr[c]);
    }
  }
}

// ---------------- mid: g0, h0 = g0@w1b^T, e = Z0@w1a^T + h0 + 2*b1 ----------------
__global__ __launch_bounds__(256) void mid_kernel(
    const unsigned short* __restrict__ Z0b, const float* __restrict__ dnm,
    const unsigned short* __restrict__ Wc1, const unsigned short* __restrict__ Wc2,
    const float* __restrict__ bias0, const float* __restrict__ bias1,
    unsigned short* __restrict__ e_b, unsigned short* __restrict__ h0T,
    unsigned short* __restrict__ G)
{
  const int tid = threadIdx.x, lane = tid & 63, w = tid >> 6;
  const int rl = lane & 15, q = lane >> 4;
  const int h = blockIdx.y;
  const int rowbase = blockIdx.x * 64;      // over B*N = 8192
  const int b = rowbase >> 11, n0 = rowbase & 2047;
  const int r0 = rowbase + w * 16;

  __shared__ unsigned short g0s[4][16][72];
  __shared__ unsigned short h0s[4][16][72];

  const unsigned short* zb = Z0b + ((size_t)h * 8192 + r0 + rl) * 128 + q * 8;

  f32x4 acc1[8] = {};
  #pragma unroll
  for (int ks = 0; ks < 4; ++ks) {
    u16x8 aF = *(const u16x8*)(zb + ks * 32);
    #pragma unroll
    for (int ct = 0; ct < 8; ++ct) {
      u16x8 bF = *(const u16x8*)(Wc1 + ((size_t)h * 128 + ct * 16 + rl) * 128 + ks * 32 + q * 8);
      acc1[ct] = mfma_bf16(aF, bF, acc1[ct]);
    }
  }

  // epilogue 1: g0 = relu((t + 2 b0)/den)
  #pragma unroll
  for (int j = 0; j < 4; ++j) {
    const int row = q * 4 + j;
    const int gr = r0 + row;
    const float den = dnm[((size_t)h * 4 + b) * N_ + (gr & 2047)];
    #pragma unroll
    for (int ct = 0; ct < 4; ++ct) {
      const int c = ct * 16 + rl;
      float g = (acc1[ct][j] + 2.f * bias0[h * 64 + c]) / den;
      unsigned short gb = f2bf(fmaxf(g, 0.f));
      g0s[w][row][c] = gb;
      G[(size_t)gr * 640 + h * 64 + c] = gb;
    }
  }
  __syncthreads();

  f32x4 acc2[4] = {};
  #pragma unroll
  for (int ks = 0; ks < 2; ++ks) {
    u16x8 aF = *(const u16x8*)&g0s[w][rl][ks * 32 + q * 8];
    #pragma unroll
    for (int ct = 0; ct < 4; ++ct) {
      u16x8 bF = *(const u16x8*)(Wc2 + ((size_t)h * 64 + ct * 16 + rl) * 64 + ks * 32 + q * 8);
      acc2[ct] = mfma_bf16(aF, bF, acc2[ct]);
    }
  }

  #pragma unroll
  for (int j = 0; j < 4; ++j) {
    const int row = q * 4 + j;
    const int gr = r0 + row;
    #pragma unroll
    for (int ct = 0; ct < 4; ++ct) {
      const int c = ct * 16 + rl;
      float h0v = acc2[ct][j];
      float ev = acc1[4 + ct][j] + h0v + 2.f * bias1[h * 64 + c];
      e_b[((size_t)h * 8192 + gr) * 64 + c] = f2bf(ev);
      h0s[w][row][c] = f2bf(h0v);
    }
  }
  __syncthreads();

  // transpose-write h0T [H*B][64][N]
  {
    u16x8 t0, t1;
    #pragma unroll
    for (int r = 0; r < 8; ++r) t0[r] = h0s[w][r][lane];
    #pragma unroll
    for (int r = 0; r < 8; ++r) t1[r] = h0s[w][8 + r][lane];
    unsigned short* dst = h0T + (((size_t)h * 4 + b) * 64 + lane) * N_ + n0 + w * 16;
    *(u16x8*)dst = t0;
    *(u16x8*)(dst + 8) = t1;
  }
}

// ---------------- pass2: g1 = relu((adj@h0 + e)/den). LDS-free, barrier-free ----------------
__global__ __launch_bounds__(256) void pass2_kernel(
    const float* __restrict__ adj, const unsigned short* __restrict__ h0T,
    const unsigned short* __restrict__ e_b, const float* __restrict__ dnm,
    unsigned short* __restrict__ G)
{
  const int tid = threadIdx.x, lane = tid & 63, w = tid >> 6;
  const int rl = lane & 15, q = lane >> 4;
  const int bh = blockIdx.y, b = bh >> 2, h = bh & 3, hb = h * 4 + b;
  const int row0 = blockIdx.x * 64 + w * 16;

  const float* aP = adj + ((size_t)bh * N_ + row0 + rl) * N_ + q * 8;
  const unsigned short* bp[4];
  #pragma unroll
  for (int ct = 0; ct < 4; ++ct)
    bp[ct] = h0T + ((size_t)hb * 64 + ct * 16 + rl) * N_ + q * 8;

  f32x4 acc[4] = {};

  #pragma unroll 2
  for (int t = 0; t < 64; ++t) {
    float4 a0 = *(const float4*)(aP + (size_t)t * 32);
    float4 a1 = *(const float4*)(aP + (size_t)t * 32 + 4);
    u16x8 af;
    af[0] = f2bf(a0.x); af[1] = f2bf(a0.y); af[2] = f2bf(a0.z); af[3] = f2bf(a0.w);
    af[4] = f2bf(a1.x); af[5] = f2bf(a1.y); af[6] = f2bf(a1.z); af[7] = f2bf(a1.w);
    #pragma unroll
    for (int ct = 0; ct < 4; ++ct) {
      u16x8 bF = *(const u16x8*)(bp[ct] + (size_t)t * 32);
      acc[ct] = mfma_bf16(af, bF, acc[ct]);
    }
  }

  #pragma unroll
  for (int j = 0; j < 4; ++j) {
    const int row = q * 4 + j, n = row0 + row;
    const float den = dnm[(size_t)hb * N_ + n];
    const unsigned short* er = e_b + ((size_t)hb * N_ + n) * 64;
    unsigned short* gr = G + ((size_t)b * N_ + n) * 640 + 256 + h * 64;
    #pragma unroll
    for (int ct = 0; ct < 4; ++ct) {
      const int c = ct * 16 + rl;
      float v = (acc[ct][j] + bf2f(er[c])) / den;
      gr[c] = f2bf(fmaxf(v, 0.f));
    }
  }
}

// ---------------- pass3: out = G @ Wcat^T + bf. LDS-free ----------------
__global__ __launch_bounds__(256) void pass3_kernel(
    const unsigned short* __restrict__ G, const unsigned short* __restrict__ Wcat,
    const float* __restrict__ bfv, float* __restrict__ out)
{
  const int tid = threadIdx.x, lane = tid & 63, w = tid >> 6;
  const int rl = lane & 15, q = lane >> 4;
  const int row0 = blockIdx.x * 64 + w * 16;   // over B*N = 8192

  const unsigned short* aP = G + (size_t)(row0 + rl) * 640 + q * 8;

  f32x4 acc[8] = {};
  #pragma unroll 4
  for (int t = 0; t < 20; ++t) {
    u16x8 aF = *(const u16x8*)(aP + (size_t)t * 32);
    #pragma unroll
    for (int ct = 0; ct < 8; ++ct) {
      u16x8 bF = *(const u16x8*)(Wcat + (size_t)(ct * 16 + rl) * 640 + t * 32 + q * 8);
      acc[ct] = mfma_bf16(aF, bF, acc[ct]);
    }
  }

  #pragma unroll
  for (int j = 0; j < 4; ++j) {
    const int row = q * 4 + j;
    float* orow = out + (size_t)(row0 + row) * 128;
    #pragma unroll
    for (int ct = 0; ct < 8; ++ct) {
      const int c = ct * 16 + rl;
      orow[c] = acc[ct][j] + bfv[c];
    }
  }
}

// ---------------- launch ----------------
extern "C" void kernel_launch(void* const* d_in, const int* in_sizes, int n_in,
                              void* d_out, int out_size, void* d_ws, size_t ws_size,
                              hipStream_t stream) {
  const float* adj = (const float*)d_in[0];
  const float* X   = (const float*)d_in[1];
  const float* w0  = (const float*)d_in[2];
  const float* b0  = (const float*)d_in[3];
  const float* w1  = (const float*)d_in[4];
  const float* b1  = (const float*)d_in[5];
  const float* Wf  = (const float*)d_in[6];
  const float* bf  = (const float*)d_in[7];
  float* out = (float*)d_out;
  char* ws = (char*)d_ws;

  unsigned short* XbT  = (unsigned short*)(ws + 0);          //  2,097,152
  unsigned short* Wc1  = (unsigned short*)(ws + 2097152);    //    131,072
  unsigned short* Wc2  = (unsigned short*)(ws + 2228224);    //     32,768
  unsigned short* Wcat = (unsigned short*)(ws + 2260992);    //    163,840
  unsigned short* Z0b  = (unsigned short*)(ws + 2424832);    //  8,388,608
  float*          dnm  = (float*)(ws + 10813440);            //    131,072
  unsigned short* e_b  = (unsigned short*)(ws + 10944512);   //  4,194,304
  unsigned short* h0T  = (unsigned short*)(ws + 15138816);   //  4,194,304
  unsigned short* G    = (unsigned short*)(ws + 19333120);   // 10,485,760  (end ~29.8 MB)

  hipLaunchKernelGGL(prep_weights, dim3(640), dim3(256), 0, stream, w0, w1, Wf, Wc1, Wc2, Wcat);
  hipLaunchKernelGGL(prep_x,       dim3(128), dim3(256), 0, stream, X, XbT, G);
  hipLaunchKernelGGL(pass1_kernel, dim3(32, 16), dim3(256), 0, stream, adj, X, XbT, Z0b, dnm);
  hipLaunchKernelGGL(mid_kernel,   dim3(128, 4), dim3(256), 0, stream, Z0b, dnm, Wc1, Wc2, b0, b1, e_b, h0T, G);
  hipLaunchKernelGGL(pass2_kernel, dim3(32, 16), dim3(256), 0, stream, adj, h0T, e_b, dnm, G);
  hipLaunchKernelGGL(pass3_kernel, dim3(128), dim3(256), 0, stream, G, Wcat, bf, out);
}

// Round 3
// 216.644 us; speedup vs baseline: 1.6298x; 1.6298x over previous
//
#include <hip/hip_runtime.h>

#define N_ 2048

typedef __attribute__((ext_vector_type(8))) __bf16 bf16x8;
typedef __attribute__((ext_vector_type(8))) unsigned short u16x8;
typedef __attribute__((ext_vector_type(4))) unsigned short u16x4;
typedef __attribute__((ext_vector_type(4))) float f32x4;

__device__ inline unsigned short f2bf(float f) {
  unsigned u = __builtin_bit_cast(unsigned, f);
  u += 0x7FFFu + ((u >> 16) & 1u);   // RNE
  return (unsigned short)(u >> 16);
}
__device__ inline float bf2f(unsigned short s) {
  unsigned u = ((unsigned)s) << 16;
  return __builtin_bit_cast(float, u);
}

__device__ inline f32x4 mfma_bf16(u16x8 a, u16x8 b, f32x4 c) {
  return __builtin_amdgcn_mfma_f32_16x16x32_bf16(
      __builtin_bit_cast(bf16x8, a), __builtin_bit_cast(bf16x8, b), c, 0, 0, 0);
}

// ---------------- prep: pack weights to bf16 ----------------
__global__ __launch_bounds__(256) void prep_weights(
    const float* __restrict__ w0, const float* __restrict__ w1,
    const float* __restrict__ Wf,
    unsigned short* __restrict__ Wc1, unsigned short* __restrict__ Wc2,
    unsigned short* __restrict__ Wcat)
{
  int idx = blockIdx.x * 256 + threadIdx.x;
  if (idx < 65536) {
    int h = idx >> 14, r = (idx >> 7) & 127, k = idx & 127;
    float v = (r < 64) ? w0[(h * 64 + r) * 128 + k]
                       : w1[(h * 64 + (r - 64)) * 192 + k];
    Wc1[idx] = f2bf(v);
  } else if (idx < 81920) {
    int i = idx - 65536;
    int h = i >> 12, r = (i >> 6) & 63, k = i & 63;
    Wc2[i] = f2bf(w1[(h * 64 + r) * 192 + 128 + k]);
  } else if (idx < 163840) {
    int i = idx - 81920;
    int d = i / 640, c = i % 640;
    float v;
    if (c < 256)      { int h = c >> 6, j = c & 63;        v = Wf[d * 512 + h * 128 + j]; }
    else if (c < 512) { int h = (c - 256) >> 6, j = (c - 256) & 63; v = Wf[d * 512 + h * 128 + 64 + j]; }
    else {
      int k = c - 512; v = 0.f;
      for (int hh = 0; hh < 4; ++hh) v += Wf[d * 512 + hh * 128 + k];
    }
    Wcat[i] = f2bf(v);
  }
}

// ---------------- prep: X -> XbT (bf16 transpose [B][128][N]) + G X-slice ----------------
__global__ __launch_bounds__(256) void prep_x(
    const float* __restrict__ X, unsigned short* __restrict__ XbT,
    unsigned short* __restrict__ G)
{
  const int tid = threadIdx.x;
  const int b = blockIdx.x >> 5;
  const int n0 = (blockIdx.x & 31) * 64;
  __shared__ float tf[64][129];
  #pragma unroll
  for (int i = 0; i < 32; ++i) {
    int e = i * 256 + tid;          // 64x128 tile
    int nl = e >> 7, c = e & 127;
    float v = X[((size_t)b * N_ + n0 + nl) * 128 + c];
    tf[nl][c] = v;
    G[((size_t)b * N_ + n0 + nl) * 640 + 512 + c] = f2bf(v);
  }
  __syncthreads();
  #pragma unroll
  for (int i = 0; i < 32; ++i) {
    int e = i * 256 + tid;
    int c = e >> 6, nl = e & 63;
    XbT[((size_t)b * 128 + c) * N_ + n0 + nl] = f2bf(tf[nl][c]);
  }
}

// ---------------- pass1: Z0 = adj@X + X (bf16), denom ----------------
// 32 rows x 128 cols per block; 4 waves in 2x2 (rowhalf x colhalf); LDS dbuf.
__global__ __launch_bounds__(256) void pass1_kernel(
    const float* __restrict__ adj, const float* __restrict__ X,
    const unsigned short* __restrict__ XbT,
    unsigned short* __restrict__ Z0b, float* __restrict__ dnm)
{
  const int tid = threadIdx.x, lane = tid & 63, w = tid >> 6;
  const int wr = w >> 1, wc = w & 1, rl = lane & 15, q = lane >> 4;
  const int bh = blockIdx.y, b = bh >> 2, h = bh & 3, hb = h * 4 + b;
  const int row0 = blockIdx.x * 32;

  __shared__ unsigned short At[2][32][40];
  __shared__ unsigned short Bt[2][128][40];
  __shared__ float rowp[32];

  const int ar = tid >> 3, ak = (tid & 7) * 4;
  const float* aP = adj + ((size_t)bh * N_ + row0 + ar) * N_ + ak;
  const int br = tid >> 1, bk = (tid & 1) * 16;
  const unsigned short* bP = XbT + ((size_t)b * 128 + br) * N_ + bk;

  f32x4 acc[4] = {};
  float rsum = 0.f;
  float4 aReg; uint4 bReg0, bReg1;

  auto issue = [&](int t) {
    aReg  = *(const float4*)(aP + (size_t)t * 32);
    bReg0 = *(const uint4*)(bP + (size_t)t * 32);
    bReg1 = *(const uint4*)(bP + (size_t)t * 32 + 8);
  };
  auto cvt_write = [&](int buf) {
    rsum += (aReg.x + aReg.y) + (aReg.z + aReg.w);
    u16x4 v;
    v[0] = f2bf(aReg.x); v[1] = f2bf(aReg.y); v[2] = f2bf(aReg.z); v[3] = f2bf(aReg.w);
    *(u16x4*)&At[buf][ar][ak] = v;
    *(uint4*)&Bt[buf][br][bk] = bReg0;
    *(uint4*)&Bt[buf][br][bk + 8] = bReg1;
  };
  auto compute = [&](int buf) {
    u16x8 aF = *(u16x8*)&At[buf][wr * 16 + rl][q * 8];
    #pragma unroll
    for (int ct = 0; ct < 4; ++ct) {
      u16x8 bF = *(u16x8*)&Bt[buf][wc * 64 + ct * 16 + rl][q * 8];
      acc[ct] = mfma_bf16(aF, bF, acc[ct]);
    }
  };

  issue(0);
  cvt_write(0);
  __syncthreads();
  for (int t = 0; t < 64; ++t) {
    const int buf = t & 1;
    if (t < 63) issue(t + 1);
    compute(buf);
    if (t < 63) cvt_write(buf ^ 1);
    __syncthreads();
  }

  // row sums: lanes (tid&7) share a row
  rsum += __shfl_xor(rsum, 1, 64);
  rsum += __shfl_xor(rsum, 2, 64);
  rsum += __shfl_xor(rsum, 4, 64);
  if ((lane & 7) == 0) rowp[w * 8 + (lane >> 3)] = rsum;
  __syncthreads();
  if (tid < 32) dnm[(size_t)hb * N_ + row0 + tid] = rowp[tid] + 1.0f;

  #pragma unroll
  for (int j = 0; j < 4; ++j) {
    const int row = wr * 16 + q * 4 + j, n = row0 + row;
    const float* xr = X + ((size_t)b * N_ + n) * 128;
    unsigned short* zr = Z0b + ((size_t)hb * N_ + n) * 128;
    #pragma unroll
    for (int ct = 0; ct < 4; ++ct) {
      const int c = wc * 64 + ct * 16 + rl;
      zr[c] = f2bf(acc[ct][j] + xr[c]);
    }
  }
}

// ---------------- mid: g0, h0 = g0@w1b^T, e = Z0@w1a^T + h0 + 2*b1 ----------------
__global__ __launch_bounds__(256) void mid_kernel(
    const unsigned short* __restrict__ Z0b, const float* __restrict__ dnm,
    const unsigned short* __restrict__ Wc1, const unsigned short* __restrict__ Wc2,
    const float* __restrict__ bias0, const float* __restrict__ bias1,
    unsigned short* __restrict__ e_b, unsigned short* __restrict__ h0T,
    unsigned short* __restrict__ G)
{
  const int tid = threadIdx.x, lane = tid & 63, w = tid >> 6;
  const int rl = lane & 15, q = lane >> 4;
  const int h = blockIdx.y;
  const int rowbase = blockIdx.x * 64;      // over B*N = 8192
  const int b = rowbase >> 11, n0 = rowbase & 2047;
  const int r0 = rowbase + w * 16;

  __shared__ unsigned short g0s[4][16][72];
  __shared__ unsigned short h0s[4][16][72];

  const unsigned short* zb = Z0b + ((size_t)h * 8192 + r0 + rl) * 128 + q * 8;

  f32x4 acc1[8] = {};
  #pragma unroll
  for (int ks = 0; ks < 4; ++ks) {
    u16x8 aF = *(const u16x8*)(zb + ks * 32);
    #pragma unroll
    for (int ct = 0; ct < 8; ++ct) {
      u16x8 bF = *(const u16x8*)(Wc1 + ((size_t)h * 128 + ct * 16 + rl) * 128 + ks * 32 + q * 8);
      acc1[ct] = mfma_bf16(aF, bF, acc1[ct]);
    }
  }

  #pragma unroll
  for (int j = 0; j < 4; ++j) {
    const int row = q * 4 + j;
    const int gr = r0 + row;
    const float den = dnm[((size_t)h * 4 + b) * N_ + (gr & 2047)];
    #pragma unroll
    for (int ct = 0; ct < 4; ++ct) {
      const int c = ct * 16 + rl;
      float g = (acc1[ct][j] + 2.f * bias0[h * 64 + c]) / den;
      unsigned short gb = f2bf(fmaxf(g, 0.f));
      g0s[w][row][c] = gb;
      G[(size_t)gr * 640 + h * 64 + c] = gb;
    }
  }
  __syncthreads();

  f32x4 acc2[4] = {};
  #pragma unroll
  for (int ks = 0; ks < 2; ++ks) {
    u16x8 aF = *(const u16x8*)&g0s[w][rl][ks * 32 + q * 8];
    #pragma unroll
    for (int ct = 0; ct < 4; ++ct) {
      u16x8 bF = *(const u16x8*)(Wc2 + ((size_t)h * 64 + ct * 16 + rl) * 64 + ks * 32 + q * 8);
      acc2[ct] = mfma_bf16(aF, bF, acc2[ct]);
    }
  }

  #pragma unroll
  for (int j = 0; j < 4; ++j) {
    const int row = q * 4 + j;
    const int gr = r0 + row;
    #pragma unroll
    for (int ct = 0; ct < 4; ++ct) {
      const int c = ct * 16 + rl;
      float h0v = acc2[ct][j];
      float ev = acc1[4 + ct][j] + h0v + 2.f * bias1[h * 64 + c];
      e_b[((size_t)h * 8192 + gr) * 64 + c] = f2bf(ev);
      h0s[w][row][c] = f2bf(h0v);
    }
  }
  __syncthreads();

  {
    u16x8 t0, t1;
    #pragma unroll
    for (int r = 0; r < 8; ++r) t0[r] = h0s[w][r][lane];
    #pragma unroll
    for (int r = 0; r < 8; ++r) t1[r] = h0s[w][8 + r][lane];
    unsigned short* dst = h0T + (((size_t)h * 4 + b) * 64 + lane) * N_ + n0 + w * 16;
    *(u16x8*)dst = t0;
    *(u16x8*)(dst + 8) = t1;
  }
}

// ---------------- pass2: g1 = relu((adj@h0 + e)/den) ----------------
// 32 rows x 64 cols per block; 4 waves 2x2; LDS dbuf.
__global__ __launch_bounds__(256) void pass2_kernel(
    const float* __restrict__ adj, const unsigned short* __restrict__ h0T,
    const unsigned short* __restrict__ e_b, const float* __restrict__ dnm,
    unsigned short* __restrict__ G)
{
  const int tid = threadIdx.x, lane = tid & 63, w = tid >> 6;
  const int wr = w >> 1, wc = w & 1, rl = lane & 15, q = lane >> 4;
  const int bh = blockIdx.y, b = bh >> 2, h = bh & 3, hb = h * 4 + b;
  const int row0 = blockIdx.x * 32;

  __shared__ unsigned short At[2][32][40];
  __shared__ unsigned short Bt[2][64][40];

  const int ar = tid >> 3, ak = (tid & 7) * 4;
  const float* aP = adj + ((size_t)bh * N_ + row0 + ar) * N_ + ak;
  const int br = tid >> 2, bk = (tid & 3) * 8;
  const unsigned short* bP = h0T + ((size_t)hb * 64 + br) * N_ + bk;

  f32x4 acc[2] = {};
  float4 aReg; uint4 bReg;

  auto issue = [&](int t) {
    aReg = *(const float4*)(aP + (size_t)t * 32);
    bReg = *(const uint4*)(bP + (size_t)t * 32);
  };
  auto cvt_write = [&](int buf) {
    u16x4 v;
    v[0] = f2bf(aReg.x); v[1] = f2bf(aReg.y); v[2] = f2bf(aReg.z); v[3] = f2bf(aReg.w);
    *(u16x4*)&At[buf][ar][ak] = v;
    *(uint4*)&Bt[buf][br][bk] = bReg;
  };
  auto compute = [&](int buf) {
    u16x8 aF = *(u16x8*)&At[buf][wr * 16 + rl][q * 8];
    #pragma unroll
    for (int ct = 0; ct < 2; ++ct) {
      u16x8 bF = *(u16x8*)&Bt[buf][wc * 32 + ct * 16 + rl][q * 8];
      acc[ct] = mfma_bf16(aF, bF, acc[ct]);
    }
  };

  issue(0);
  cvt_write(0);
  __syncthreads();
  for (int t = 0; t < 64; ++t) {
    const int buf = t & 1;
    if (t < 63) issue(t + 1);
    compute(buf);
    if (t < 63) cvt_write(buf ^ 1);
    __syncthreads();
  }

  #pragma unroll
  for (int j = 0; j < 4; ++j) {
    const int row = wr * 16 + q * 4 + j, n = row0 + row;
    const float den = dnm[(size_t)hb * N_ + n];
    const unsigned short* er = e_b + ((size_t)hb * N_ + n) * 64;
    unsigned short* gr = G + ((size_t)b * N_ + n) * 640 + 256 + h * 64;
    #pragma unroll
    for (int ct = 0; ct < 2; ++ct) {
      const int c = wc * 32 + ct * 16 + rl;
      float v = (acc[ct][j] + bf2f(er[c])) / den;
      gr[c] = f2bf(fmaxf(v, 0.f));
    }
  }
}

// ---------------- pass3: out = G @ Wcat^T + bf ----------------
// 16 rows per block; 4 waves: colhalf x khalf; LDS reduce over k-halves.
__global__ __launch_bounds__(256) void pass3_kernel(
    const unsigned short* __restrict__ G, const unsigned short* __restrict__ Wcat,
    const float* __restrict__ bfv, float* __restrict__ out)
{
  const int tid = threadIdx.x, lane = tid & 63, w = tid >> 6;
  const int wc = w & 1, kc = w >> 1, rl = lane & 15, q = lane >> 4;
  const int row0 = blockIdx.x * 16;   // over B*N = 8192

  __shared__ float red[2][16][68];

  const unsigned short* aP = G + (size_t)(row0 + rl) * 640 + kc * 320 + q * 8;
  const unsigned short* wP = Wcat + (size_t)kc * 320 + q * 8;

  f32x4 acc[4] = {};
  #pragma unroll
  for (int t = 0; t < 10; ++t) {
    u16x8 aF = *(const u16x8*)(aP + (size_t)t * 32);
    #pragma unroll
    for (int ct = 0; ct < 4; ++ct) {
      u16x8 bF = *(const u16x8*)(wP + (size_t)(wc * 64 + ct * 16 + rl) * 640 + t * 32);
      acc[ct] = mfma_bf16(aF, bF, acc[ct]);
    }
  }

  if (kc == 1) {
    #pragma unroll
    for (int j = 0; j < 4; ++j)
      #pragma unroll
      for (int ct = 0; ct < 4; ++ct)
        red[wc][q * 4 + j][ct * 16 + rl] = acc[ct][j];
  }
  __syncthreads();
  if (kc == 0) {
    #pragma unroll
    for (int j = 0; j < 4; ++j) {
      const int row = q * 4 + j;
      float* orow = out + (size_t)(row0 + row) * 128;
      #pragma unroll
      for (int ct = 0; ct < 4; ++ct) {
        const int c = wc * 64 + ct * 16 + rl;
        orow[c] = acc[ct][j] + red[wc][row][ct * 16 + rl] + bfv[c];
      }
    }
  }
}

// ---------------- launch ----------------
extern "C" void kernel_launch(void* const* d_in, const int* in_sizes, int n_in,
                              void* d_out, int out_size, void* d_ws, size_t ws_size,
                              hipStream_t stream) {
  const float* adj = (const float*)d_in[0];
  const float* X   = (const float*)d_in[1];
  const float* w0  = (const float*)d_in[2];
  const float* b0  = (const float*)d_in[3];
  const float* w1  = (const float*)d_in[4];
  const float* b1  = (const float*)d_in[5];
  const float* Wf  = (const float*)d_in[6];
  const float* bf  = (const float*)d_in[7];
  float* out = (float*)d_out;
  char* ws = (char*)d_ws;

  unsigned short* XbT  = (unsigned short*)(ws + 0);          //  2,097,152
  unsigned short* Wc1  = (unsigned short*)(ws + 2097152);    //    131,072
  unsigned short* Wc2  = (unsigned short*)(ws + 2228224);    //     32,768
  unsigned short* Wcat = (unsigned short*)(ws + 2260992);    //    163,840
  unsigned short* Z0b  = (unsigned short*)(ws + 2424832);    //  8,388,608
  float*          dnm  = (float*)(ws + 10813440);            //    131,072
  unsigned short* e_b  = (unsigned short*)(ws + 10944512);   //  4,194,304
  unsigned short* h0T  = (unsigned short*)(ws + 15138816);   //  4,194,304
  unsigned short* G    = (unsigned short*)(ws + 19333120);   // 10,485,760  (end ~29.8 MB)

  hipLaunchKernelGGL(prep_weights, dim3(640), dim3(256), 0, stream, w0, w1, Wf, Wc1, Wc2, Wcat);
  hipLaunchKernelGGL(prep_x,       dim3(128), dim3(256), 0, stream, X, XbT, G);
  hipLaunchKernelGGL(pass1_kernel, dim3(64, 16), dim3(256), 0, stream, adj, X, XbT, Z0b, dnm);
  hipLaunchKernelGGL(mid_kernel,   dim3(128, 4), dim3(256), 0, stream, Z0b, dnm, Wc1, Wc2, b0, b1, e_b, h0T, G);
  hipLaunchKernelGGL(pass2_kernel, dim3(64, 16), dim3(256), 0, stream, adj, h0T, e_b, dnm, G);
  hipLaunchKernelGGL(pass3_kernel, dim3(512), dim3(256), 0, stream, G, Wcat, bf, out);
}